// Round 4
// baseline (835.131 us; speedup 1.0000x reference)
//
#include <hip/hip_runtime.h>

#define NNODES 100000
#define NEDGES 1600000
#define D 64
#define EPSN 1e-12f
#define NBUK ((NNODES + 255) >> 8)   // 391 buckets of 256 nodes
#define BCAP 5120                    // per-bucket capacity (mean 4096, max ~4350)

// ---------------------------------------------------------------------------
// P1: bucket scatter. bucket = dst>>8; one atomicAdd gives count AND slot.
// Packed value = (src<<8) | (dst&255)  (src < 2^17 so fits with room).
// Write frontier per bucket is contiguous -> lines fill fully, write-amp ~1.
// ---------------------------------------------------------------------------
__global__ __launch_bounds__(256) void bucket_scatter_kernel(
    const int* __restrict__ src,
    const int* __restrict__ dst,
    int* __restrict__ bukcur,
    int* __restrict__ ebuf)
{
    const int e = blockIdx.x * 256 + threadIdx.x;
    if (e >= NEDGES) return;
    const int d = dst[e];
    const int b = d >> 8;
    const int p = atomicAdd(&bukcur[b], 1);
    if (p < BCAP) ebuf[(size_t)b * BCAP + p] = (src[e] << 8) | (d & 255);
}

// ---------------------------------------------------------------------------
// Exclusive scan over the 391 bucket counts -> bucket start offsets.
// ---------------------------------------------------------------------------
__global__ void bukscan_kernel(const int* __restrict__ bukcur,
                               int* __restrict__ bukstart) {
    __shared__ int s[512];
    const int t = threadIdx.x;
    const int v = (t < NBUK) ? min(bukcur[t], BCAP) : 0;
    int val = v;
    s[t] = val;
    __syncthreads();
    for (int off = 1; off < 512; off <<= 1) {
        int add = (t >= off) ? s[t - off] : 0;
        __syncthreads();
        val += add;
        s[t] = val;
        __syncthreads();
    }
    if (t < NBUK) bukstart[t] = val - v;   // exclusive
}

// ---------------------------------------------------------------------------
// P2: per-bucket placement. LDS count of the bucket's 256 nodes + LDS scan
// produces rowptr for free; LDS cursors place srcs into a contiguous ~16KB
// CSR window (L2-resident writes, no global atomics).
// ---------------------------------------------------------------------------
__global__ __launch_bounds__(256) void bucket_place_kernel(
    const int* __restrict__ bukcur,
    const int* __restrict__ bukstart,
    const int* __restrict__ ebuf,
    int* __restrict__ rowptr,
    int* __restrict__ ssrc)
{
    __shared__ int lcnt[256];   // counts, then exclusive offsets
    __shared__ int lcur[256];   // placement cursors
    __shared__ int s[256];      // scan temp
    const int b = blockIdx.x;
    const int t = threadIdx.x;
    lcnt[t] = 0;
    lcur[t] = 0;
    __syncthreads();

    const int cnt  = min(bukcur[b], BCAP);
    const int base = bukstart[b];
    const int* eb  = ebuf + (size_t)b * BCAP;

    // count local nodes
    for (int i = t; i < cnt; i += 256) atomicAdd(&lcnt[eb[i] & 255], 1);
    __syncthreads();

    // exclusive scan of lcnt
    const int v = lcnt[t];
    int val = v;
    s[t] = val;
    __syncthreads();
    for (int off = 1; off < 256; off <<= 1) {
        int add = (t >= off) ? s[t - off] : 0;
        __syncthreads();
        val += add;
        s[t] = val;
        __syncthreads();
    }
    const int myoff = val - v;   // exclusive offset within bucket
    __syncthreads();
    lcnt[t] = myoff;             // repurpose lcnt as offsets
    const int node = b * 256 + t;
    if (node < NNODES) rowptr[node] = base + myoff;
    if (b == 0 && t == 0) rowptr[NNODES] = NEDGES;
    __syncthreads();

    // place
    for (int i = t; i < cnt; i += 256) {
        const int pv = eb[i];
        const int d = pv & 255;
        const int p = atomicAdd(&lcur[d], 1);
        ssrc[base + lcnt[d] + p] = pv >> 8;
    }
}

// ---------------------------------------------------------------------------
// Gather: agg[n] = sum_{s in row(n)} feat[s].  Quarter-wave (16 lanes) per
// node, float4 per lane => one 256B coalesced request per edge-row.
// ---------------------------------------------------------------------------
__global__ __launch_bounds__(256) void gather_kernel(
    const float* __restrict__ feat,
    const int* __restrict__ rowptr,
    const int* __restrict__ ssrc,
    float* __restrict__ agg)
{
    const int tid = threadIdx.x;
    const int quarter = tid >> 4;            // 0..15
    const int f = tid & 15;                  // float4 slot within row
    const int node = blockIdx.x * 16 + quarter;
    if (node >= NNODES) return;

    const int beg = rowptr[node];
    const int end = rowptr[node + 1];
    const float* fb = feat + (size_t)f * 4;

    float ax = 0.f, ay = 0.f, az = 0.f, aw = 0.f;
    int j = beg;
    for (; j + 4 <= end; j += 4) {
        const int s0 = ssrc[j + 0];
        const int s1 = ssrc[j + 1];
        const int s2 = ssrc[j + 2];
        const int s3 = ssrc[j + 3];
        const float4 v0 = *reinterpret_cast<const float4*>(&fb[(size_t)s0 * D]);
        const float4 v1 = *reinterpret_cast<const float4*>(&fb[(size_t)s1 * D]);
        const float4 v2 = *reinterpret_cast<const float4*>(&fb[(size_t)s2 * D]);
        const float4 v3 = *reinterpret_cast<const float4*>(&fb[(size_t)s3 * D]);
        ax += v0.x + v1.x + v2.x + v3.x;
        ay += v0.y + v1.y + v2.y + v3.y;
        az += v0.z + v1.z + v2.z + v3.z;
        aw += v0.w + v1.w + v2.w + v3.w;
    }
    for (; j < end; ++j) {
        const int s = ssrc[j];
        const float4 v = *reinterpret_cast<const float4*>(&fb[(size_t)s * D]);
        ax += v.x; ay += v.y; az += v.z; aw += v.w;
    }
    float4 r; r.x = ax; r.y = ay; r.z = az; r.w = aw;
    *reinterpret_cast<float4*>(&agg[(size_t)node * D + f * 4]) = r;
}

// ---------------------------------------------------------------------------
// Transform: out[n][o] = bias[o] + sum_k agg[n][k]*Wl[o][k] + xin[n][k]*Wr[o][k]
// One wave per block; lane o holds Wl[o][:], Wr[o][:] in 128 registers.
// ---------------------------------------------------------------------------
template <bool RELU_NORM>
__global__ __launch_bounds__(64, 2) void transform_kernel(
    const float* __restrict__ agg,
    const float* __restrict__ xin,
    const float* __restrict__ Wl,
    const float* __restrict__ bl,
    const float* __restrict__ Wr,
    float* __restrict__ out)
{
    __shared__ float rowbuf[2][D];
    const int lane = threadIdx.x;

    float wl[D], wr[D];
    #pragma unroll
    for (int kb = 0; kb < 16; ++kb) {
        const float4 a = *reinterpret_cast<const float4*>(&Wl[lane * D + kb * 4]);
        const float4 b = *reinterpret_cast<const float4*>(&Wr[lane * D + kb * 4]);
        wl[kb * 4 + 0] = a.x; wl[kb * 4 + 1] = a.y;
        wl[kb * 4 + 2] = a.z; wl[kb * 4 + 3] = a.w;
        wr[kb * 4 + 0] = b.x; wr[kb * 4 + 1] = b.y;
        wr[kb * 4 + 2] = b.z; wr[kb * 4 + 3] = b.w;
    }
    const float bias = bl[lane];

    for (int node = blockIdx.x; node < NNODES; node += gridDim.x) {
        if (lane < 16) {
            *reinterpret_cast<float4*>(&rowbuf[0][lane * 4]) =
                *reinterpret_cast<const float4*>(&agg[(size_t)node * D + lane * 4]);
        } else if (lane < 32) {
            const int f = lane & 15;
            *reinterpret_cast<float4*>(&rowbuf[1][f * 4]) =
                *reinterpret_cast<const float4*>(&xin[(size_t)node * D + f * 4]);
        }
        __syncthreads();

        float oacc = bias;
        #pragma unroll
        for (int kb = 0; kb < 16; ++kb) {
            const float4 a  = *reinterpret_cast<const float4*>(&rowbuf[0][kb * 4]);
            const float4 xv = *reinterpret_cast<const float4*>(&rowbuf[1][kb * 4]);
            oacc += a.x  * wl[kb * 4 + 0] + a.y  * wl[kb * 4 + 1]
                  + a.z  * wl[kb * 4 + 2] + a.w  * wl[kb * 4 + 3];
            oacc += xv.x * wr[kb * 4 + 0] + xv.y * wr[kb * 4 + 1]
                  + xv.z * wr[kb * 4 + 2] + xv.w * wr[kb * 4 + 3];
        }
        if (RELU_NORM) {
            oacc = fmaxf(oacc, 0.f);
            float ss = oacc * oacc;
            #pragma unroll
            for (int m = 1; m < 64; m <<= 1) ss += __shfl_xor(ss, m, 64);
            oacc = oacc / fmaxf(sqrtf(ss), EPSN);
        }
        out[(size_t)node * D + lane] = oacc;
        __syncthreads();
    }
}

extern "C" void kernel_launch(void* const* d_in, const int* in_sizes, int n_in,
                              void* d_out, int out_size, void* d_ws, size_t ws_size,
                              hipStream_t stream) {
    const float* x   = (const float*)d_in[0];
    const int* eidx  = (const int*)d_in[1];
    // d_in[2] = edge_feature (unused)
    const float* W1l = (const float*)d_in[3];
    const float* b1l = (const float*)d_in[4];
    const float* W1r = (const float*)d_in[5];
    const float* W2l = (const float*)d_in[6];
    const float* b2l = (const float*)d_in[7];
    const float* W2r = (const float*)d_in[8];
    float* out = (float*)d_out;

    const int* src = eidx;            // edge_index[0]
    const int* dst = eidx + NEDGES;   // edge_index[1]

    // workspace layout (16B-aligned chunks)
    char* ws = (char*)d_ws;
    int* bukcur   = (int*)ws;  ws += ((size_t)NBUK * 4 + 15) / 16 * 16;
    int* bukstart = (int*)ws;  ws += ((size_t)NBUK * 4 + 15) / 16 * 16;
    int* rowptr   = (int*)ws;  ws += ((size_t)(NNODES + 1) * 4 + 15) / 16 * 16;
    int* ssrc     = (int*)ws;  ws += ((size_t)NEDGES * 4 + 15) / 16 * 16;
    int* ebuf     = (int*)ws;  ws += ((size_t)NBUK * BCAP * 4 + 15) / 16 * 16;
    float* agg    = (float*)ws;               // [N, D]
    float* h      = out;                      // layer-1 output lives in d_out

    dim3 blk(256);
    dim3 egrid((NEDGES + 255) / 256);
    dim3 ggrid((NNODES + 15) / 16);
    dim3 tgrid(4096);
    dim3 tblk(64);

    // ---- CSR build (shared by both layers) ----
    hipMemsetAsync(bukcur, 0, (size_t)NBUK * 4, stream);
    bucket_scatter_kernel<<<egrid, blk, 0, stream>>>(src, dst, bukcur, ebuf);
    bukscan_kernel<<<1, 512, 0, stream>>>(bukcur, bukstart);
    bucket_place_kernel<<<NBUK, blk, 0, stream>>>(bukcur, bukstart, ebuf,
                                                  rowptr, ssrc);

    // ---- layer 1: h = normalize(relu(agg@W1l^T + b1l + x@W1r^T)) ----
    gather_kernel<<<ggrid, blk, 0, stream>>>(x, rowptr, ssrc, agg);
    transform_kernel<true><<<tgrid, tblk, 0, stream>>>(agg, x, W1l, b1l, W1r, h);

    // ---- layer 2: out = agg(h)@W2l^T + b2l + h@W2r^T ----
    gather_kernel<<<ggrid, blk, 0, stream>>>(h, rowptr, ssrc, agg);
    transform_kernel<false><<<tgrid, tblk, 0, stream>>>(agg, h, W2l, b2l, W2r, out);
}

// Round 5
// 366.376 us; speedup vs baseline: 2.2794x; 2.2794x over previous
//
#include <hip/hip_runtime.h>

#define NNODES 100000
#define NEDGES 1600000
#define D 64
#define EPSN 1e-12f
#define NBUK ((NNODES + 255) >> 8)   // 391 buckets of 256 nodes
#define NSLICE 64                    // contention-spreading sub-counters
#define CAPS 128                     // per-(bucket,slice) capacity (mean 64)

// ---------------------------------------------------------------------------
// P1: bucket scatter. bucket = dst>>8; slice = blockIdx&63 spreads the
// atomic counter 64-way (contention ~64/address instead of ~4100).
// Packed value = (src<<8) | (dst&255).  Frontier-contiguous writes.
// ---------------------------------------------------------------------------
__global__ __launch_bounds__(256) void bucket_scatter_kernel(
    const int* __restrict__ src,
    const int* __restrict__ dst,
    int* __restrict__ bukcur,
    int* __restrict__ ebuf)
{
    const int e = blockIdx.x * 256 + threadIdx.x;
    if (e >= NEDGES) return;
    const int d = dst[e];
    const int b = d >> 8;
    const int slice = blockIdx.x & (NSLICE - 1);
    const int c = b * NSLICE + slice;
    const int p = atomicAdd(&bukcur[c], 1);
    if (p < CAPS) ebuf[((size_t)c << 7) + p] = (src[e] << 8) | (d & 255);
}

// ---------------------------------------------------------------------------
// Exclusive scan over bucket totals (sum of 64 slice counts each).
// ---------------------------------------------------------------------------
__global__ void bukscan_kernel(const int* __restrict__ bukcur,
                               int* __restrict__ bukstart) {
    __shared__ int s[512];
    const int t = threadIdx.x;
    int v = 0;
    if (t < NBUK) {
        #pragma unroll 8
        for (int sl = 0; sl < NSLICE; ++sl)
            v += min(bukcur[t * NSLICE + sl], CAPS);
    }
    int val = v;
    s[t] = val;
    __syncthreads();
    for (int off = 1; off < 512; off <<= 1) {
        int add = (t >= off) ? s[t - off] : 0;
        __syncthreads();
        val += add;
        s[t] = val;
        __syncthreads();
    }
    if (t < NBUK) bukstart[t] = val - v;   // exclusive
}

// ---------------------------------------------------------------------------
// P2: per-bucket placement. LDS count + LDS scan of the bucket's 256 nodes
// gives rowptr; LDS cursors place srcs into a contiguous CSR window.
// Slices are walked with a flat predicated loop (CAPS=128 -> shifts).
// ---------------------------------------------------------------------------
__global__ __launch_bounds__(256) void bucket_place_kernel(
    const int* __restrict__ bukcur,
    const int* __restrict__ bukstart,
    const int* __restrict__ ebuf,
    int* __restrict__ rowptr,
    int* __restrict__ ssrc)
{
    __shared__ int lcnt[256];   // counts -> exclusive offsets
    __shared__ int lcur[256];   // placement cursors
    __shared__ int stmp[256];   // scan temp
    __shared__ int scnt[NSLICE];
    const int b = blockIdx.x;
    const int t = threadIdx.x;
    lcnt[t] = 0;
    lcur[t] = 0;
    if (t < NSLICE) scnt[t] = min(bukcur[b * NSLICE + t], CAPS);
    __syncthreads();

    const int base = bukstart[b];
    const int* eb = ebuf + ((size_t)b * NSLICE << 7);

    // count local nodes (predicated flat walk over 64*128 slots)
    for (int i = t; i < NSLICE * CAPS; i += 256) {
        if ((i & (CAPS - 1)) < scnt[i >> 7]) atomicAdd(&lcnt[eb[i] & 255], 1);
    }
    __syncthreads();

    // exclusive scan of lcnt
    const int v = lcnt[t];
    int val = v;
    stmp[t] = val;
    __syncthreads();
    for (int off = 1; off < 256; off <<= 1) {
        int add = (t >= off) ? stmp[t - off] : 0;
        __syncthreads();
        val += add;
        stmp[t] = val;
        __syncthreads();
    }
    const int myoff = val - v;
    __syncthreads();
    lcnt[t] = myoff;             // repurpose as offsets
    const int node = b * 256 + t;
    if (node < NNODES) rowptr[node] = base + myoff;
    if (b == 0 && t == 0) rowptr[NNODES] = NEDGES;
    __syncthreads();

    // place
    for (int i = t; i < NSLICE * CAPS; i += 256) {
        if ((i & (CAPS - 1)) < scnt[i >> 7]) {
            const int pv = eb[i];
            const int d = pv & 255;
            const int p = atomicAdd(&lcur[d], 1);
            ssrc[base + lcnt[d] + p] = pv >> 8;
        }
    }
}

// ---------------------------------------------------------------------------
// Gather: agg[n] = sum_{s in row(n)} feat[s].  Quarter-wave (16 lanes) per
// node, float4 per lane => one 256B coalesced request per edge-row.
// ---------------------------------------------------------------------------
__global__ __launch_bounds__(256) void gather_kernel(
    const float* __restrict__ feat,
    const int* __restrict__ rowptr,
    const int* __restrict__ ssrc,
    float* __restrict__ agg)
{
    const int tid = threadIdx.x;
    const int quarter = tid >> 4;            // 0..15
    const int f = tid & 15;                  // float4 slot within row
    const int node = blockIdx.x * 16 + quarter;
    if (node >= NNODES) return;

    const int beg = rowptr[node];
    const int end = rowptr[node + 1];
    const float* fb = feat + (size_t)f * 4;

    float ax = 0.f, ay = 0.f, az = 0.f, aw = 0.f;
    int j = beg;
    for (; j + 4 <= end; j += 4) {
        const int s0 = ssrc[j + 0];
        const int s1 = ssrc[j + 1];
        const int s2 = ssrc[j + 2];
        const int s3 = ssrc[j + 3];
        const float4 v0 = *reinterpret_cast<const float4*>(&fb[(size_t)s0 * D]);
        const float4 v1 = *reinterpret_cast<const float4*>(&fb[(size_t)s1 * D]);
        const float4 v2 = *reinterpret_cast<const float4*>(&fb[(size_t)s2 * D]);
        const float4 v3 = *reinterpret_cast<const float4*>(&fb[(size_t)s3 * D]);
        ax += v0.x + v1.x + v2.x + v3.x;
        ay += v0.y + v1.y + v2.y + v3.y;
        az += v0.z + v1.z + v2.z + v3.z;
        aw += v0.w + v1.w + v2.w + v3.w;
    }
    for (; j < end; ++j) {
        const int s = ssrc[j];
        const float4 v = *reinterpret_cast<const float4*>(&fb[(size_t)s * D]);
        ax += v.x; ay += v.y; az += v.z; aw += v.w;
    }
    float4 r; r.x = ax; r.y = ay; r.z = az; r.w = aw;
    *reinterpret_cast<float4*>(&agg[(size_t)node * D + f * 4]) = r;
}

// ---------------------------------------------------------------------------
// Transform: out[n][o] = bias[o] + sum_k agg[n][k]*Wl[o][k] + xin[n][k]*Wr[o][k]
// One wave per block; lane o holds Wl[o][:], Wr[o][:] in 128 registers.
// ---------------------------------------------------------------------------
template <bool RELU_NORM>
__global__ __launch_bounds__(64, 2) void transform_kernel(
    const float* __restrict__ agg,
    const float* __restrict__ xin,
    const float* __restrict__ Wl,
    const float* __restrict__ bl,
    const float* __restrict__ Wr,
    float* __restrict__ out)
{
    __shared__ float rowbuf[2][D];
    const int lane = threadIdx.x;

    float wl[D], wr[D];
    #pragma unroll
    for (int kb = 0; kb < 16; ++kb) {
        const float4 a = *reinterpret_cast<const float4*>(&Wl[lane * D + kb * 4]);
        const float4 b = *reinterpret_cast<const float4*>(&Wr[lane * D + kb * 4]);
        wl[kb * 4 + 0] = a.x; wl[kb * 4 + 1] = a.y;
        wl[kb * 4 + 2] = a.z; wl[kb * 4 + 3] = a.w;
        wr[kb * 4 + 0] = b.x; wr[kb * 4 + 1] = b.y;
        wr[kb * 4 + 2] = b.z; wr[kb * 4 + 3] = b.w;
    }
    const float bias = bl[lane];

    for (int node = blockIdx.x; node < NNODES; node += gridDim.x) {
        if (lane < 16) {
            *reinterpret_cast<float4*>(&rowbuf[0][lane * 4]) =
                *reinterpret_cast<const float4*>(&agg[(size_t)node * D + lane * 4]);
        } else if (lane < 32) {
            const int f = lane & 15;
            *reinterpret_cast<float4*>(&rowbuf[1][f * 4]) =
                *reinterpret_cast<const float4*>(&xin[(size_t)node * D + f * 4]);
        }
        __syncthreads();

        float oacc = bias;
        #pragma unroll
        for (int kb = 0; kb < 16; ++kb) {
            const float4 a  = *reinterpret_cast<const float4*>(&rowbuf[0][kb * 4]);
            const float4 xv = *reinterpret_cast<const float4*>(&rowbuf[1][kb * 4]);
            oacc += a.x  * wl[kb * 4 + 0] + a.y  * wl[kb * 4 + 1]
                  + a.z  * wl[kb * 4 + 2] + a.w  * wl[kb * 4 + 3];
            oacc += xv.x * wr[kb * 4 + 0] + xv.y * wr[kb * 4 + 1]
                  + xv.z * wr[kb * 4 + 2] + xv.w * wr[kb * 4 + 3];
        }
        if (RELU_NORM) {
            oacc = fmaxf(oacc, 0.f);
            float ss = oacc * oacc;
            #pragma unroll
            for (int m = 1; m < 64; m <<= 1) ss += __shfl_xor(ss, m, 64);
            oacc = oacc / fmaxf(sqrtf(ss), EPSN);
        }
        out[(size_t)node * D + lane] = oacc;
        __syncthreads();
    }
}

extern "C" void kernel_launch(void* const* d_in, const int* in_sizes, int n_in,
                              void* d_out, int out_size, void* d_ws, size_t ws_size,
                              hipStream_t stream) {
    const float* x   = (const float*)d_in[0];
    const int* eidx  = (const int*)d_in[1];
    // d_in[2] = edge_feature (unused)
    const float* W1l = (const float*)d_in[3];
    const float* b1l = (const float*)d_in[4];
    const float* W1r = (const float*)d_in[5];
    const float* W2l = (const float*)d_in[6];
    const float* b2l = (const float*)d_in[7];
    const float* W2r = (const float*)d_in[8];
    float* out = (float*)d_out;

    const int* src = eidx;            // edge_index[0]
    const int* dst = eidx + NEDGES;   // edge_index[1]

    // workspace layout (16B-aligned chunks)
    char* ws = (char*)d_ws;
    int* bukcur   = (int*)ws;  ws += ((size_t)NBUK * NSLICE * 4 + 15) / 16 * 16;
    int* bukstart = (int*)ws;  ws += ((size_t)NBUK * 4 + 15) / 16 * 16;
    int* rowptr   = (int*)ws;  ws += ((size_t)(NNODES + 1) * 4 + 15) / 16 * 16;
    int* ssrc     = (int*)ws;  ws += ((size_t)NEDGES * 4 + 15) / 16 * 16;
    int* ebuf     = (int*)ws;  ws += ((size_t)NBUK * NSLICE * CAPS * 4 + 15) / 16 * 16;
    float* agg    = (float*)ws;               // [N, D]
    float* h      = out;                      // layer-1 output lives in d_out

    dim3 blk(256);
    dim3 egrid((NEDGES + 255) / 256);
    dim3 ggrid((NNODES + 15) / 16);
    dim3 tgrid(4096);
    dim3 tblk(64);

    // ---- CSR build (shared by both layers) ----
    hipMemsetAsync(bukcur, 0, (size_t)NBUK * NSLICE * 4, stream);
    bucket_scatter_kernel<<<egrid, blk, 0, stream>>>(src, dst, bukcur, ebuf);
    bukscan_kernel<<<1, 512, 0, stream>>>(bukcur, bukstart);
    bucket_place_kernel<<<NBUK, blk, 0, stream>>>(bukcur, bukstart, ebuf,
                                                  rowptr, ssrc);

    // ---- layer 1: h = normalize(relu(agg@W1l^T + b1l + x@W1r^T)) ----
    gather_kernel<<<ggrid, blk, 0, stream>>>(x, rowptr, ssrc, agg);
    transform_kernel<true><<<tgrid, tblk, 0, stream>>>(agg, x, W1l, b1l, W1r, h);

    // ---- layer 2: out = agg(h)@W2l^T + b2l + h@W2r^T ----
    gather_kernel<<<ggrid, blk, 0, stream>>>(h, rowptr, ssrc, agg);
    transform_kernel<false><<<tgrid, tblk, 0, stream>>>(agg, h, W2l, b2l, W2r, out);
}